// Round 13
// baseline (520.803 us; speedup 1.0000x reference)
//
#include <hip/hip_runtime.h>
#include <hip/hip_bf16.h>
#include <stdint.h>

#define B_   32
#define C_   512
#define HW_  3136
#define HID_ 128
#define WPX  32     // pixels per wave (= per block; 64-thread blocks)
#define HP   136    // hlds pitch in bf16 elems (272B rows -> 2-way bank alias, free)
#define EPS_ 1e-5f

using frag8 = __attribute__((ext_vector_type(8))) short;  // 8 bf16 (4 VGPRs)
using f32x4 = __attribute__((ext_vector_type(4))) float;  // 4 fp32 acc

__device__ __forceinline__ short f2bf(float f) {
    union { float f; uint32_t u; } v; v.f = f;
    uint32_t u = v.u;
    u += 0x7fffu + ((u >> 16) & 1u);   // RNE
    return (short)(u >> 16);
}

// ---------------------------------------------------------------------------
// Prep (UNCHANGED, proven): fp32 weights -> bf16 panels; panel(mt,kt) is
// 16x32 bf16, element (i, 8q+j) at offset ((q*16+i)*8 + j); one A-frag load
// per wave is a single coalesced 1KB read. Folds BN into scale/shift.
// ---------------------------------------------------------------------------
__global__ __launch_bounds__(256) void prep_kernel(
    const float* __restrict__ w1_rgb, const float* __restrict__ w2_rgb,
    const float* __restrict__ w1_inf, const float* __restrict__ w2_inf,
    const float* __restrict__ rm_rgb, const float* __restrict__ rv_rgb,
    const float* __restrict__ g_rgb,  const float* __restrict__ b_rgb,
    const float* __restrict__ rm_inf, const float* __restrict__ rv_inf,
    const float* __restrict__ g_inf,  const float* __restrict__ b_inf,
    short* __restrict__ w1p_rgb, short* __restrict__ w1p_inf,
    short* __restrict__ w2p_rgb, short* __restrict__ w2p_inf,
    float* __restrict__ ss)
{
    int t = blockIdx.x * 256 + threadIdx.x;   // 0 .. 65535
    int p = t >> 9, w = t & 511;
    int q = w >> 7, r = (w >> 3) & 15, j = w & 7;
    {   // w1: M=128, K=512 -> 8 x 16 panels
        int mt = p >> 4, kt = p & 15;
        int m = mt * 16 + r, k = kt * 32 + q * 8 + j;
        w1p_rgb[t] = f2bf(w1_rgb[m * C_ + k]);
        w1p_inf[t] = f2bf(w1_inf[m * C_ + k]);
    }
    {   // w2: M=512, K=128 -> 32 x 4 panels
        int mt = p >> 2, kt = p & 3;
        int m = mt * 16 + r, k = kt * 32 + q * 8 + j;
        w2p_rgb[t] = f2bf(w2_rgb[m * HID_ + k]);
        w2p_inf[t] = f2bf(w2_inf[m * HID_ + k]);
    }
    if (t < 128) {
        float sc = g_rgb[t] * rsqrtf(rv_rgb[t] + EPS_);
        ss[t] = sc; ss[128 + t] = b_rgb[t] - rm_rgb[t] * sc;
    } else if (t < 256) {
        int i = t - 128;
        float sc = g_inf[i] * rsqrtf(rv_inf[i] + EPS_);
        ss[256 + i] = sc; ss[384 + i] = b_inf[i] - rm_inf[i] * sc;
    }
}

// ---------------------------------------------------------------------------
// Fused, BARRIER-FREE: one independent wave per (sample b, 32-pixel tile).
//   Key insight: the MFMA B-frag (lane(q,i16) holds 8 consecutive channels of
//   one pixel) matches x's global [channel][pixel] layout, so x goes
//   global -> regs -> MFMA with NO LDS staging and NO barriers. Each wave:
//     stage1: acc1[8mt][2nt] = w1 @ x (K=512), all 128 hid x 32 px
//     BN+ReLU -> wave-private hlds [px][hid] (compiler lgkmcnt orders it)
//     stage2: 8 passes of 64 out-ch: acc2[4][2] = w2 @ h -> global
//   ~12 free-running waves/CU at independent phases keep the memory pipes
//   continuously fed (the fillBuffer concurrency model: 6.6 TB/s @ 10% occ).
// ---------------------------------------------------------------------------
__global__ __launch_bounds__(64, 3) void fused_kernel(
    const float* __restrict__ x, const int* __restrict__ mod,
    const short* __restrict__ w1p_rgb, const short* __restrict__ w1p_inf,
    const short* __restrict__ w2p_rgb, const short* __restrict__ w2p_inf,
    const float* __restrict__ ss, float* __restrict__ out)
{
    __shared__ short hlds[WPX * HP];   // 8704 B, wave-private (1-wave block)

    const int lane = threadIdx.x;      // 0..63
    const int i16  = lane & 15;        // frag col index
    const int q    = lane >> 4;        // frag quad
    const int b    = blockIdx.y;
    const int p0   = blockIdx.x * WPX;

    const int is_rgb = (mod[b] == 1);
    const short* __restrict__ w1p = is_rgb ? w1p_rgb : w1p_inf;
    const short* __restrict__ w2p = is_rgb ? w2p_rgb : w2p_inf;
    const float* __restrict__ scale = ss + (is_rgb ? 0 : 256);
    const float* __restrict__ shift = scale + 128;

    // this lane's two pixel columns (nt = 0, 1)
    const float* xc0 = x + ((size_t)b * C_) * HW_ + p0 + i16;
    const float* xc1 = xc0 + 16;

    // ---- Stage 1: acc1[mt][nt], 128 hid x 32 px, K = 512 (16 ktiles) ----
    f32x4 acc1[8][2];
    #pragma unroll
    for (int mt = 0; mt < 8; ++mt) {
        acc1[mt][0] = (f32x4){0.f, 0.f, 0.f, 0.f};
        acc1[mt][1] = (f32x4){0.f, 0.f, 0.f, 0.f};
    }

    #pragma unroll
    for (int kt = 0; kt < 16; ++kt) {
        // B-frags straight from global: ch = kt*32 + q*8 + j, px fixed.
        // Per load instr: 16 consecutive px (64B) x 4 channel groups.
        float xf0[8], xf1[8];
        #pragma unroll
        for (int j = 0; j < 8; ++j) {
            size_t off = (size_t)(kt * 32 + q * 8 + j) * HW_;
            xf0[j] = xc0[off];
            xf1[j] = xc1[off];
        }
        frag8 b0, b1;
        #pragma unroll
        for (int j = 0; j < 8; ++j) { b0[j] = f2bf(xf0[j]); b1[j] = f2bf(xf1[j]); }

        #pragma unroll
        for (int mt = 0; mt < 8; ++mt) {
            frag8 af = *(const frag8*)(w1p + ((mt * 16 + kt) << 9) + lane * 8);
            acc1[mt][0] = __builtin_amdgcn_mfma_f32_16x16x32_bf16(af, b0, acc1[mt][0], 0, 0, 0);
            acc1[mt][1] = __builtin_amdgcn_mfma_f32_16x16x32_bf16(af, b1, acc1[mt][1], 0, 0, 0);
        }
    }

    // ---- BN + ReLU -> hlds [px][hid] (wave-internal; no barrier needed) ----
    #pragma unroll
    for (int mt = 0; mt < 8; ++mt) {
        int mbase = mt * 16 + q * 4;
        float s0 = scale[mbase + 0], s1 = scale[mbase + 1];
        float s2 = scale[mbase + 2], s3 = scale[mbase + 3];
        float h0 = shift[mbase + 0], h1 = shift[mbase + 1];
        float h2 = shift[mbase + 2], h3 = shift[mbase + 3];
        #pragma unroll
        for (int nt = 0; nt < 2; ++nt) {
            int px = nt * 16 + i16;
            float v0 = fmaxf(acc1[mt][nt][0] * s0 + h0, 0.f);
            float v1 = fmaxf(acc1[mt][nt][1] * s1 + h1, 0.f);
            float v2 = fmaxf(acc1[mt][nt][2] * s2 + h2, 0.f);
            float v3 = fmaxf(acc1[mt][nt][3] * s3 + h3, 0.f);
            short4 pk = make_short4(f2bf(v0), f2bf(v1), f2bf(v2), f2bf(v3));
            *(short4*)(&hlds[px * HP + mbase]) = pk;
        }
    }

    // ---- Stage 2: 8 passes x 64 out-ch; acc2[4][2] = 32 regs ----
    #pragma unroll 1
    for (int pass = 0; pass < 8; ++pass) {
        f32x4 acc2[4][2];
        #pragma unroll
        for (int mt = 0; mt < 4; ++mt) {
            acc2[mt][0] = (f32x4){0.f, 0.f, 0.f, 0.f};
            acc2[mt][1] = (f32x4){0.f, 0.f, 0.f, 0.f};
        }
        #pragma unroll
        for (int kt = 0; kt < 4; ++kt) {
            frag8 h0 = *(const frag8*)(&hlds[(0 * 16 + i16) * HP + kt * 32 + q * 8]);
            frag8 h1 = *(const frag8*)(&hlds[(1 * 16 + i16) * HP + kt * 32 + q * 8]);
            #pragma unroll
            for (int mt = 0; mt < 4; ++mt) {
                int mtg = pass * 4 + mt;
                frag8 af = *(const frag8*)(w2p + ((mtg * 4 + kt) << 9) + lane * 8);
                acc2[mt][0] = __builtin_amdgcn_mfma_f32_16x16x32_bf16(af, h0, acc2[mt][0], 0, 0, 0);
                acc2[mt][1] = __builtin_amdgcn_mfma_f32_16x16x32_bf16(af, h1, acc2[mt][1], 0, 0, 0);
            }
        }
        // stores: per instr 16 consecutive px (64B) x 4 rows
        #pragma unroll
        for (int mt = 0; mt < 4; ++mt) {
            int mrow = (pass * 4 + mt) * 16 + q * 4;
            #pragma unroll
            for (int nt = 0; nt < 2; ++nt) {
                int col = p0 + nt * 16 + i16;
                float* op = out + ((size_t)(b * C_ + mrow)) * HW_ + col;
                op[0 * HW_] = acc2[mt][nt][0];
                op[1 * HW_] = acc2[mt][nt][1];
                op[2 * HW_] = acc2[mt][nt][2];
                op[3 * HW_] = acc2[mt][nt][3];
            }
        }
    }
}

extern "C" void kernel_launch(void* const* d_in, const int* in_sizes, int n_in,
                              void* d_out, int out_size, void* d_ws, size_t ws_size,
                              hipStream_t stream) {
    const float* x      = (const float*)d_in[0];
    const int*   mod    = (const int*)d_in[1];
    const float* w1_rgb = (const float*)d_in[2];
    const float* rm_rgb = (const float*)d_in[3];
    const float* rv_rgb = (const float*)d_in[4];
    const float* g_rgb  = (const float*)d_in[5];
    const float* b_rgb  = (const float*)d_in[6];
    const float* w2_rgb = (const float*)d_in[7];
    const float* w1_inf = (const float*)d_in[8];
    const float* rm_inf = (const float*)d_in[9];
    const float* rv_inf = (const float*)d_in[10];
    const float* g_inf  = (const float*)d_in[11];
    const float* b_inf  = (const float*)d_in[12];
    const float* w2_inf = (const float*)d_in[13];
    float* out = (float*)d_out;

    char* ws = (char*)d_ws;
    short* w1p_rgb = (short*)(ws + 0);
    short* w1p_inf = (short*)(ws + 131072);
    short* w2p_rgb = (short*)(ws + 262144);
    short* w2p_inf = (short*)(ws + 393216);
    float* ss      = (float*)(ws + 524288);   // 512 floats

    prep_kernel<<<256, 256, 0, stream>>>(
        w1_rgb, w2_rgb, w1_inf, w2_inf,
        rm_rgb, rv_rgb, g_rgb, b_rgb,
        rm_inf, rv_inf, g_inf, b_inf,
        w1p_rgb, w1p_inf, w2p_rgb, w2p_inf, ss);

    dim3 grid(HW_ / WPX, B_);
    fused_kernel<<<grid, 64, 0, stream>>>(
        x, mod, w1p_rgb, w1p_inf, w2p_rgb, w2p_inf, ss, out);
}

// Round 14
// 377.590 us; speedup vs baseline: 1.3793x; 1.3793x over previous
//
#include <hip/hip_runtime.h>
#include <hip/hip_bf16.h>
#include <stdint.h>

#define B_   32
#define C_   512
#define HW_  3136
#define HID_ 128
#define PT   64     // pixels per block tile
#define XP   72     // xlds pitch (bf16 elems)
#define HP   136    // hlds pitch
#define EPS_ 1e-5f

using frag8 = __attribute__((ext_vector_type(8))) short;  // 8 bf16 (4 VGPRs)
using f32x4 = __attribute__((ext_vector_type(4))) float;  // 4 fp32 acc

__device__ __forceinline__ short f2bf(float f) {
    union { float f; uint32_t u; } v; v.f = f;
    uint32_t u = v.u;
    u += 0x7fffu + ((u >> 16) & 1u);   // RNE
    return (short)(u >> 16);
}

// Barrier that does NOT drain vmem: ds_writes made visible (lgkmcnt(0)),
// in-flight global prefetch loads survive the barrier (T4, learn_hip).
#define BARRIER_KEEP_VMEM() do {                                  \
    asm volatile("s_waitcnt lgkmcnt(0)" ::: "memory");            \
    __builtin_amdgcn_s_barrier();                                 \
    asm volatile("" ::: "memory");                                \
} while (0)

// ---------------------------------------------------------------------------
// Prep (proven): fp32 weights -> bf16 panels; panel(mt,kt) is 16x32 bf16,
// element (i, 8q+j) at offset ((q*16+i)*8 + j). Folds BN into scale/shift.
// ---------------------------------------------------------------------------
__global__ __launch_bounds__(256) void prep_kernel(
    const float* __restrict__ w1_rgb, const float* __restrict__ w2_rgb,
    const float* __restrict__ w1_inf, const float* __restrict__ w2_inf,
    const float* __restrict__ rm_rgb, const float* __restrict__ rv_rgb,
    const float* __restrict__ g_rgb,  const float* __restrict__ b_rgb,
    const float* __restrict__ rm_inf, const float* __restrict__ rv_inf,
    const float* __restrict__ g_inf,  const float* __restrict__ b_inf,
    short* __restrict__ w1p_rgb, short* __restrict__ w1p_inf,
    short* __restrict__ w2p_rgb, short* __restrict__ w2p_inf,
    float* __restrict__ ss)
{
    int t = blockIdx.x * 256 + threadIdx.x;   // 0 .. 65535
    int p = t >> 9, w = t & 511;
    int q = w >> 7, r = (w >> 3) & 15, j = w & 7;
    {   // w1: M=128, K=512 -> 8 x 16 panels
        int mt = p >> 4, kt = p & 15;
        int m = mt * 16 + r, k = kt * 32 + q * 8 + j;
        w1p_rgb[t] = f2bf(w1_rgb[m * C_ + k]);
        w1p_inf[t] = f2bf(w1_inf[m * C_ + k]);
    }
    {   // w2: M=512, K=128 -> 32 x 4 panels
        int mt = p >> 2, kt = p & 3;
        int m = mt * 16 + r, k = kt * 32 + q * 8 + j;
        w2p_rgb[t] = f2bf(w2_rgb[m * HID_ + k]);
        w2p_inf[t] = f2bf(w2_inf[m * HID_ + k]);
    }
    if (t < 128) {
        float sc = g_rgb[t] * rsqrtf(rv_rgb[t] + EPS_);
        ss[t] = sc; ss[128 + t] = b_rgb[t] - rm_rgb[t] * sc;
    } else if (t < 256) {
        int i = t - 128;
        float sc = g_inf[i] * rsqrtf(rv_inf[i] + EPS_);
        ss[256 + i] = sc; ss[384 + i] = b_inf[i] - rm_inf[i] * sc;
    }
}

// ---------------------------------------------------------------------------
// Fused, DEPTH-2 pipelined (r11 base = 125.9us):
//   steady state per chunk k: convert+write k (waits loads issued at k-2),
//   prefetch x(k+2), prefetch af(k+1), KEEP_VMEM barrier, MFMA k (af loaded
//   at k-1, already landed). FIFO: no wait ever drains a younger prefetch.
//   stage2: 4 passes of acc[2][4] (r11). LDS: hlds aliases the 2 xlds bufs.
// ---------------------------------------------------------------------------
__global__ __launch_bounds__(256) void fused_kernel(
    const float* __restrict__ x, const int* __restrict__ mod,
    const short* __restrict__ w1p_rgb, const short* __restrict__ w1p_inf,
    const short* __restrict__ w2p_rgb, const short* __restrict__ w2p_inf,
    const float* __restrict__ ss, float* __restrict__ out)
{
    __shared__ short smem[2 * PT * XP];  // 2 x-chunk buffers; reused as hlds
    short* hlds = smem;                  // [pixel][hid(128)] pitch 136; 8704<=9216

    const int tid  = threadIdx.x;
    const int lane = tid & 63;
    const int wave = tid >> 6;
    const int i16  = lane & 15;   // frag col index
    const int q    = lane >> 4;   // frag quad
    const int b    = blockIdx.y;
    const int p0   = blockIdx.x * PT;

    const int is_rgb = (mod[b] == 1);
    const short* __restrict__ w1p = is_rgb ? w1p_rgb : w1p_inf;
    const short* __restrict__ w2p = is_rgb ? w2p_rgb : w2p_inf;
    const float* __restrict__ scale = ss + (is_rgb ? 0 : 256);
    const float* __restrict__ shift = scale + 128;

    f32x4 acc1[2][4];
    #pragma unroll
    for (int mt = 0; mt < 2; ++mt)
        #pragma unroll
        for (int nt = 0; nt < 4; ++nt)
            acc1[mt][nt] = (f32x4){0.f, 0.f, 0.f, 0.f};

    const int px = tid & 63;          // staging: this thread's pixel
    const int cg = tid >> 6;          // staging: channel group (16 ch each)
    const float* xbase = x + ((size_t)b * C_) * HW_ + p0 + px;

    float xr[2][16];       // depth-2 x prefetch banks (bank = chunk parity)
    frag8 afr[2][2][2];    // depth-1 af prefetch banks [bank][kk][mt]

    // prologue: x chunks 0,1 and af ktiles of chunk 0
    #pragma unroll
    for (int it = 0; it < 4; ++it) {
        int c = cg * 16 + it * 4;
        xr[0][it * 4 + 0] = xbase[(size_t)(c + 0) * HW_];
        xr[0][it * 4 + 1] = xbase[(size_t)(c + 1) * HW_];
        xr[0][it * 4 + 2] = xbase[(size_t)(c + 2) * HW_];
        xr[0][it * 4 + 3] = xbase[(size_t)(c + 3) * HW_];
    }
    #pragma unroll
    for (int it = 0; it < 4; ++it) {
        int c = 64 + cg * 16 + it * 4;
        xr[1][it * 4 + 0] = xbase[(size_t)(c + 0) * HW_];
        xr[1][it * 4 + 1] = xbase[(size_t)(c + 1) * HW_];
        xr[1][it * 4 + 2] = xbase[(size_t)(c + 2) * HW_];
        xr[1][it * 4 + 3] = xbase[(size_t)(c + 3) * HW_];
    }
    #pragma unroll
    for (int kk = 0; kk < 2; ++kk)
        #pragma unroll
        for (int mt = 0; mt < 2; ++mt)
            afr[0][kk][mt] = *(const frag8*)(w1p + (((wave * 2 + mt) * 16 + kk) << 9) + lane * 8);

    #pragma unroll
    for (int k = 0; k < 8; ++k) {           // chunk index; all indices static
        const int bank = k & 1;
        short* xw = &smem[bank * (PT * XP)];

        // convert + write chunk k (vmcnt wait: loads issued 2 iters ago)
        #pragma unroll
        for (int it = 0; it < 4; ++it) {
            int c = cg * 16 + it * 4;
            short4 pk = make_short4(f2bf(xr[bank][it * 4 + 0]), f2bf(xr[bank][it * 4 + 1]),
                                    f2bf(xr[bank][it * 4 + 2]), f2bf(xr[bank][it * 4 + 3]));
            *(short4*)(&xw[px * XP + c]) = pk;
        }

        // prefetch x chunk k+2 into the bank just freed
        if (k + 2 < 8) {
            #pragma unroll
            for (int it = 0; it < 4; ++it) {
                int c = (k + 2) * 64 + cg * 16 + it * 4;
                xr[bank][it * 4 + 0] = xbase[(size_t)(c + 0) * HW_];
                xr[bank][it * 4 + 1] = xbase[(size_t)(c + 1) * HW_];
                xr[bank][it * 4 + 2] = xbase[(size_t)(c + 2) * HW_];
                xr[bank][it * 4 + 3] = xbase[(size_t)(c + 3) * HW_];
            }
        }
        // prefetch af of chunk k+1 (L2-resident panels; lands in 1 iter)
        if (k + 1 < 8) {
            #pragma unroll
            for (int kk = 0; kk < 2; ++kk)
                #pragma unroll
                for (int mt = 0; mt < 2; ++mt) {
                    int kt = (k + 1) * 2 + kk;
                    afr[bank ^ 1][kk][mt] =
                        *(const frag8*)(w1p + (((wave * 2 + mt) * 16 + kt) << 9) + lane * 8);
                }
        }
        __builtin_amdgcn_sched_barrier(0);   // pin: all loads issue pre-barrier
        BARRIER_KEEP_VMEM();                 // ds_writes visible; prefetch flies

        #pragma unroll
        for (int kk = 0; kk < 2; ++kk) {
            frag8 bfr[4];
            #pragma unroll
            for (int nt = 0; nt < 4; ++nt)
                bfr[nt] = *(const frag8*)(&xw[(nt * 16 + i16) * XP + kk * 32 + q * 8]);
            #pragma unroll
            for (int mt = 0; mt < 2; ++mt)
                #pragma unroll
                for (int nt = 0; nt < 4; ++nt)
                    acc1[mt][nt] = __builtin_amdgcn_mfma_f32_16x16x32_bf16(
                        afr[bank][kk][mt], bfr[nt], acc1[mt][nt], 0, 0, 0);
        }
        // dbuf WAR: iter k+2's writes to this buffer follow barrier(k+1),
        // which follows each wave's lgkmcnt(0)-covered iter-k reads.
    }

    // all waves done reading smem-as-xlds before hlds overwrites it
    __syncthreads();

    // ---- BN + ReLU -> hlds (bf16, pixel-major) ----
    #pragma unroll
    for (int mt = 0; mt < 2; ++mt) {
        int mbase = wave * 32 + mt * 16 + q * 4;
        float s0 = scale[mbase + 0], s1 = scale[mbase + 1];
        float s2 = scale[mbase + 2], s3 = scale[mbase + 3];
        float h0 = shift[mbase + 0], h1 = shift[mbase + 1];
        float h2 = shift[mbase + 2], h3 = shift[mbase + 3];
        #pragma unroll
        for (int nt = 0; nt < 4; ++nt) {
            int p = nt * 16 + i16;
            float v0 = fmaxf(acc1[mt][nt][0] * s0 + h0, 0.f);
            float v1 = fmaxf(acc1[mt][nt][1] * s1 + h1, 0.f);
            float v2 = fmaxf(acc1[mt][nt][2] * s2 + h2, 0.f);
            float v3 = fmaxf(acc1[mt][nt][3] * s3 + h3, 0.f);
            short4 pk = make_short4(f2bf(v0), f2bf(v1), f2bf(v2), f2bf(v3));
            *(short4*)(&hlds[p * HP + mbase]) = pk;
        }
    }
    __syncthreads();

    // ---- Stage 2: out(512x64); FOUR passes, 2 M-tiles x 4 N-tiles each ----
    #pragma unroll 1
    for (int pass = 0; pass < 4; ++pass) {
        f32x4 acc2[2][4];
        #pragma unroll
        for (int mt = 0; mt < 2; ++mt)
            #pragma unroll
            for (int nt = 0; nt < 4; ++nt)
                acc2[mt][nt] = (f32x4){0.f, 0.f, 0.f, 0.f};

        #pragma unroll
        for (int kt = 0; kt < 4; ++kt) {
            frag8 af2[2], bfr[4];
            #pragma unroll
            for (int mt = 0; mt < 2; ++mt) {
                int mtg = pass * 8 + wave * 2 + mt;
                af2[mt] = *(const frag8*)(w2p + ((mtg * 4 + kt) << 9) + lane * 8);
            }
            #pragma unroll
            for (int nt = 0; nt < 4; ++nt)
                bfr[nt] = *(const frag8*)(&hlds[(nt * 16 + i16) * HP + kt * 32 + q * 8]);
            #pragma unroll
            for (int mt = 0; mt < 2; ++mt)
                #pragma unroll
                for (int nt = 0; nt < 4; ++nt)
                    acc2[mt][nt] = __builtin_amdgcn_mfma_f32_16x16x32_bf16(
                        af2[mt], bfr[nt], acc2[mt][nt], 0, 0, 0);
        }
        // store fp32
        #pragma unroll
        for (int mt = 0; mt < 2; ++mt) {
            int mrow = (pass * 8 + wave * 2 + mt) * 16 + q * 4;
            #pragma unroll
            for (int nt = 0; nt < 4; ++nt) {
                int col = p0 + nt * 16 + i16;
                float* op = out + ((size_t)(b * C_ + mrow)) * HW_ + col;
                op[0 * HW_] = acc2[mt][nt][0];
                op[1 * HW_] = acc2[mt][nt][1];
                op[2 * HW_] = acc2[mt][nt][2];
                op[3 * HW_] = acc2[mt][nt][3];
            }
        }
    }
}

extern "C" void kernel_launch(void* const* d_in, const int* in_sizes, int n_in,
                              void* d_out, int out_size, void* d_ws, size_t ws_size,
                              hipStream_t stream) {
    const float* x      = (const float*)d_in[0];
    const int*   mod    = (const int*)d_in[1];
    const float* w1_rgb = (const float*)d_in[2];
    const float* rm_rgb = (const float*)d_in[3];
    const float* rv_rgb = (const float*)d_in[4];
    const float* g_rgb  = (const float*)d_in[5];
    const float* b_rgb  = (const float*)d_in[6];
    const float* w2_rgb = (const float*)d_in[7];
    const float* w1_inf = (const float*)d_in[8];
    const float* rm_inf = (const float*)d_in[9];
    const float* rv_inf = (const float*)d_in[10];
    const float* g_inf  = (const float*)d_in[11];
    const float* b_inf  = (const float*)d_in[12];
    const float* w2_inf = (const float*)d_in[13];
    float* out = (float*)d_out;

    char* ws = (char*)d_ws;
    short* w1p_rgb = (short*)(ws + 0);
    short* w1p_inf = (short*)(ws + 131072);
    short* w2p_rgb = (short*)(ws + 262144);
    short* w2p_inf = (short*)(ws + 393216);
    float* ss      = (float*)(ws + 524288);   // 512 floats

    prep_kernel<<<256, 256, 0, stream>>>(
        w1_rgb, w2_rgb, w1_inf, w2_inf,
        rm_rgb, rv_rgb, g_rgb, b_rgb,
        rm_inf, rv_inf, g_inf, b_inf,
        w1p_rgb, w1p_inf, w2p_rgb, w2p_inf, ss);

    dim3 grid(HW_ / PT, B_);
    fused_kernel<<<grid, 256, 0, stream>>>(
        x, mod, w1p_rgb, w1p_inf, w2p_rgb, w2p_inf, ss, out);
}